// Round 1
// baseline (230.593 us; speedup 1.0000x reference)
//
#include <hip/hip_runtime.h>
#include <stdint.h>

// Problem: TiLinear — int8 GEMM [32768,1024]x[1024,1024]^T with int32 acc,
// global range-estimate, round-shift requantize to int8, plus exp scalar.
// Inputs arrive as int32 (sign-extended int8); output buffer is int32.

#define MM 32768
#define NN 1024
#define KK 1024
#define BM 128
#define BN 128
#define BK 128

typedef __attribute__((ext_vector_type(4))) int i32x4;
typedef __attribute__((ext_vector_type(16))) int i32x16;

__device__ __forceinline__ int pack4(int a, int b, int c, int d) {
  return (int)((unsigned)(a & 0xff) | ((unsigned)(b & 0xff) << 8) |
               ((unsigned)(c & 0xff) << 16) | ((unsigned)(d & 0xff) << 24));
}

__global__ void k_init(unsigned* slot) {
  if (threadIdx.x == 0) *slot = 0u;
}

// Pack sign-extended-int8-in-int32 -> raw int8. n must be a multiple of 16.
__global__ void k_pack(const int* __restrict__ src, int8_t* __restrict__ dst, int n) {
  long t = (long)blockIdx.x * blockDim.x + threadIdx.x;
  long stride = (long)gridDim.x * blockDim.x;
  for (long i = t * 16; i < (long)n; i += stride * 16) {
    const i32x4* s = (const i32x4*)(src + i);
    i32x4 a0 = s[0], a1 = s[1], a2 = s[2], a3 = s[3];
    i32x4 o;
    o[0] = pack4(a0[0], a0[1], a0[2], a0[3]);
    o[1] = pack4(a1[0], a1[1], a1[2], a1[3]);
    o[2] = pack4(a2[0], a2[1], a2[2], a2[3]);
    o[3] = pack4(a3[0], a3[1], a3[2], a3[3]);
    *(i32x4*)(dst + i) = o;
  }
}

// PHASE 0: GEMM -> global max|acc| via atomicMax into maxslot.
// PHASE 1: GEMM -> requant with shift derived from *maxslot -> store int32.
// PACKED: operands are int8 (from d_ws); else raw int32 (packed inline).
template <bool PACKED, int PHASE>
__global__ __launch_bounds__(256, 2)
void k_gemm(const void* __restrict__ Ap, const void* __restrict__ Bp,
            int* __restrict__ out, unsigned* __restrict__ maxslot) {
  __shared__ int8_t As[BM * BK];
  __shared__ int8_t Bs[BN * BK];

  const int tid  = threadIdx.x;
  const int lane = tid & 63;
  const int w    = tid >> 6;
  const int wr   = w >> 1;   // 2x2 wave grid, each wave owns 64x64
  const int wc   = w & 1;
  const int bid  = blockIdx.x;
  const int bn   = bid & (NN / BN - 1);  // 8 col-blocks: adjacent bids share A panel
  const int bm   = bid >> 3;
  const int m0   = bm * BM;
  const int n0   = bn * BN;

  i32x16 acc[2][2];
#pragma unroll
  for (int i = 0; i < 2; ++i)
#pragma unroll
    for (int j = 0; j < 2; ++j) acc[i][j] = 0;

  for (int kt = 0; kt < KK / BK; ++kt) {
    const int k0 = kt * BK;
    __syncthreads();
    // Stage A and B tiles (128x128 int8 each) with XOR swizzle on the write.
#pragma unroll
    for (int j = 0; j < 4; ++j) {
      const int fb  = (j * 256 + tid) * 16;  // flat byte in 16KB tile
      const int row = fb >> 7;               // BK = 128 bytes per row
      const int swz = fb ^ ((row & 7) << 4);
      const int col = fb & 127;
      i32x4 av, bv;
      if (PACKED) {
        const int8_t* A8 = (const int8_t*)Ap;
        const int8_t* B8 = (const int8_t*)Bp;
        av = *(const i32x4*)(A8 + (size_t)(m0 + row) * KK + k0 + col);
        bv = *(const i32x4*)(B8 + (size_t)(n0 + row) * KK + k0 + col);
      } else {
        const int* sa = (const int*)Ap + (size_t)(m0 + row) * KK + k0 + col;
        const int* sb = (const int*)Bp + (size_t)(n0 + row) * KK + k0 + col;
#pragma unroll
        for (int q = 0; q < 4; ++q) {
          i32x4 ta = ((const i32x4*)sa)[q];
          i32x4 tb = ((const i32x4*)sb)[q];
          av[q] = pack4(ta[0], ta[1], ta[2], ta[3]);
          bv[q] = pack4(tb[0], tb[1], tb[2], tb[3]);
        }
      }
      *(i32x4*)(As + swz) = av;
      *(i32x4*)(Bs + swz) = bv;
    }
    __syncthreads();

#pragma unroll
    for (int ks = 0; ks < 4; ++ks) {
      i32x4 af[2], bf[2];
#pragma unroll
      for (int mi = 0; mi < 2; ++mi) {
        const int row = wr * 64 + mi * 32 + (lane & 31);
        int addr = row * BK + ks * 32 + ((lane >> 5) << 4);
        addr ^= (row & 7) << 4;
        af[mi] = *(const i32x4*)(As + addr);
      }
#pragma unroll
      for (int ni = 0; ni < 2; ++ni) {
        const int row = wc * 64 + ni * 32 + (lane & 31);
        int addr = row * BK + ks * 32 + ((lane >> 5) << 4);
        addr ^= (row & 7) << 4;
        bf[ni] = *(const i32x4*)(Bs + addr);
      }
#pragma unroll
      for (int mi = 0; mi < 2; ++mi)
#pragma unroll
        for (int ni = 0; ni < 2; ++ni)
          acc[mi][ni] = __builtin_amdgcn_mfma_i32_32x32x32_i8(
              af[mi], bf[ni], acc[mi][ni], 0, 0, 0);
    }
  }

  if (PHASE == 0) {
    int mx = 0;
#pragma unroll
    for (int mi = 0; mi < 2; ++mi)
#pragma unroll
      for (int ni = 0; ni < 2; ++ni)
#pragma unroll
        for (int rg = 0; rg < 16; ++rg) {
          int x = acc[mi][ni][rg];
          int a = x < 0 ? -x : x;
          mx = a > mx ? a : mx;
        }
#pragma unroll
    for (int off = 32; off >= 1; off >>= 1) {
      int o = __shfl_xor(mx, off);
      mx = o > mx ? o : mx;
    }
    if (lane == 0) atomicMax(maxslot, (unsigned)mx);
  } else {
    const unsigned r = *maxslot;
    // bits = ceil(log2(max(r,1))) computed exactly in integer arithmetic
    const int bits  = (r <= 1u) ? 0 : (32 - __clz((int)(r - 1u)));
    const int shift = bits - 7;  // BITWIDTH = 7
#pragma unroll
    for (int mi = 0; mi < 2; ++mi)
#pragma unroll
      for (int ni = 0; ni < 2; ++ni) {
        const int mbase = m0 + wr * 64 + mi * 32;
        const int ncol  = n0 + wc * 64 + ni * 32 + (lane & 31);
#pragma unroll
        for (int rg = 0; rg < 16; ++rg) {
          const int x = acc[mi][ni][rg];
          int v;
          if (shift > 0) {
            // RoundShift: floor-div + bit-below rounding, clip to [-127,127]
            v = (x >> shift) + ((x >> (shift - 1)) & 1);
            v = v > 127 ? 127 : (v < -127 ? -127 : v);
          } else {
            v = (int)(int8_t)x;  // wraparound int8 cast per reference
          }
          const int mrow = mbase + (rg & 3) + ((rg >> 2) << 3) + ((lane >> 5) << 2);
          out[(size_t)mrow * NN + ncol] = v;
        }
      }
  }
}

__global__ void k_final(int* __restrict__ out, const int* __restrict__ exp_in,
                        const int* __restrict__ wexp) {
  if (threadIdx.x == 0) {
    const unsigned r = *(const unsigned*)(out + (size_t)MM * NN);
    const int bits  = (r <= 1u) ? 0 : (32 - __clz((int)(r - 1u)));
    const int shift = bits - 7;
    out[(size_t)MM * NN] = *exp_in + *wexp + (shift > 0 ? shift : 0);
  }
}

extern "C" void kernel_launch(void* const* d_in, const int* in_sizes, int n_in,
                              void* d_out, int out_size, void* d_ws, size_t ws_size,
                              hipStream_t stream) {
  const int* act    = (const int*)d_in[0];
  const int* wgt    = (const int*)d_in[1];
  const int* exp_in = (const int*)d_in[2];
  const int* wexp   = (const int*)d_in[3];
  int* out          = (int*)d_out;
  unsigned* maxslot = (unsigned*)(out + (size_t)MM * NN);  // spare exp slot

  const size_t need = (size_t)(MM + NN) * KK + 256;
  const int gemm_grid = (MM / BM) * (NN / BN);  // 2048

  k_init<<<1, 64, 0, stream>>>(maxslot);

  if (ws_size >= need) {
    int8_t* a8 = (int8_t*)d_ws;
    int8_t* w8 = a8 + (size_t)MM * KK;
    k_pack<<<2048, 256, 0, stream>>>(act, a8, MM * KK);
    k_pack<<<256, 256, 0, stream>>>(wgt, w8, NN * KK);
    k_gemm<true, 0><<<gemm_grid, 256, 0, stream>>>(a8, w8, out, maxslot);
    k_gemm<true, 1><<<gemm_grid, 256, 0, stream>>>(a8, w8, out, maxslot);
  } else {
    k_gemm<false, 0><<<gemm_grid, 256, 0, stream>>>(act, wgt, out, maxslot);
    k_gemm<false, 1><<<gemm_grid, 256, 0, stream>>>(act, wgt, out, maxslot);
  }

  k_final<<<1, 64, 0, stream>>>(out, exp_in, wexp);
}

// Round 2
// 198.669 us; speedup vs baseline: 1.1607x; 1.1607x over previous
//
#include <hip/hip_runtime.h>
#include <stdint.h>

// TiLinear: int8 GEMM [32768,1024] x [1024,1024]^T (int32 acc) -> global
// range-estimate -> round-shift requantize to int8 (stored as int32) + exp.
//
// Plan: pack int32->int8 operands (ws), ONE MFMA GEMM that stores raw int32
// acc to d_out and atomicMax's |acc| into the spare exp slot, then an
// in-place BW-bound requant pass over d_out, then a 1-thread exp fixup.

#define MM 32768
#define NN 1024
#define KK 1024
#define BM 128
#define BN 128
#define BK 128
#define NKT (KK / BK)

typedef __attribute__((ext_vector_type(4))) int i32x4;
typedef __attribute__((ext_vector_type(16))) int i32x16;

__device__ __forceinline__ int pack4(int a, int b, int c, int d) {
  return (int)((unsigned)(a & 0xff) | ((unsigned)(b & 0xff) << 8) |
               ((unsigned)(c & 0xff) << 16) | ((unsigned)(d & 0xff) << 24));
}

__global__ void k_init(unsigned* slot) {
  if (threadIdx.x == 0) *slot = 0u;
}

// Pack sign-extended-int8-in-int32 -> raw int8. n multiple of 16.
__global__ void k_pack(const int* __restrict__ src, int8_t* __restrict__ dst, int n) {
  long t = (long)blockIdx.x * blockDim.x + threadIdx.x;
  long stride = (long)gridDim.x * blockDim.x;
  for (long i = t * 16; i < (long)n; i += stride * 16) {
    const i32x4* s = (const i32x4*)(src + i);
    i32x4 a0 = s[0], a1 = s[1], a2 = s[2], a3 = s[3];
    i32x4 o;
    o[0] = pack4(a0[0], a0[1], a0[2], a0[3]);
    o[1] = pack4(a1[0], a1[1], a1[2], a1[3]);
    o[2] = pack4(a2[0], a2[1], a2[2], a2[3]);
    o[3] = pack4(a3[0], a3[1], a3[2], a3[3]);
    *(i32x4*)(dst + i) = o;
  }
}

// GEMM: 128x128 tile, BK=128 (i8), 4 waves (2x2), dbuf LDS 64KB.
// PACKED: global_load_lds from int8 operands with pre-swizzled source.
// else:   reg-staged from int32 with inline pack (fallback if ws too small).
// Output: raw int32 acc -> out, wave-max |acc| -> atomicMax(maxslot).
template <bool PACKED>
__global__ __launch_bounds__(256, 2)
void k_gemm(const void* __restrict__ Ap, const void* __restrict__ Bp,
            int* __restrict__ out, unsigned* __restrict__ maxslot) {
  __shared__ int8_t As[2][BM * BK];
  __shared__ int8_t Bs[2][BN * BK];

  const int tid  = threadIdx.x;
  const int lane = tid & 63;
  const int w    = tid >> 6;
  const int wr   = w >> 1;   // 2x2 wave grid, each wave owns 64x64 of C
  const int wc   = w & 1;

  // XCD-bijective swizzle (2048 wgs, 8 XCDs, 256-wg contiguous chunk each):
  // keeps one XCD's A-panel working set ~4MB = its L2.
  const int orig = blockIdx.x;
  const int wgid = ((orig & 7) << 8) + (orig >> 3);
  const int bn = wgid & (NN / BN - 1);  // adjacent wgids share the A panel
  const int bm = wgid >> 3;
  const int m0 = bm * BM;
  const int n0 = bn * BN;

  i32x16 acc[2][2];
#pragma unroll
  for (int i = 0; i < 2; ++i)
#pragma unroll
    for (int j = 0; j < 2; ++j) acc[i][j] = 0;

  // Stage K-tile kt into buffer buf.
  // LDS physical byte p holds logical tile element l where
  // l = (p & ~127) | ((p & 127) ^ ((row&7)<<4)), row = p>>7.  (XOR is
  // within-row, so row bits match.)  gload_lds writes linearly at
  // uniform_base + lane*16, so the SOURCE address carries the swizzle.
  auto stage = [&](int buf, int kt) {
    const int k0 = kt * BK;
    if constexpr (PACKED) {
      const int8_t* A8 = (const int8_t*)Ap;
      const int8_t* B8 = (const int8_t*)Bp;
#pragma unroll
      for (int q = 0; q < 4; ++q) {
        const int p   = (w * 4 + q) * 1024 + lane * 16;
        const int row = p >> 7;
        const int col = (p & 127) ^ ((row & 7) << 4);
        __builtin_amdgcn_global_load_lds(
            (const __attribute__((address_space(1))) void*)(A8 + (size_t)(m0 + row) * KK + k0 + col),
            (__attribute__((address_space(3))) void*)(&As[buf][(w * 4 + q) * 1024]),
            16, 0, 0);
        __builtin_amdgcn_global_load_lds(
            (const __attribute__((address_space(1))) void*)(B8 + (size_t)(n0 + row) * KK + k0 + col),
            (__attribute__((address_space(3))) void*)(&Bs[buf][(w * 4 + q) * 1024]),
            16, 0, 0);
      }
    } else {
      const int* A32 = (const int*)Ap;
      const int* B32 = (const int*)Bp;
#pragma unroll
      for (int q = 0; q < 4; ++q) {
        const int p   = (w * 4 + q) * 1024 + lane * 16;
        const int row = p >> 7;
        const int col = (p & 127) ^ ((row & 7) << 4);
        const int* sa = A32 + (size_t)(m0 + row) * KK + k0 + col;
        const int* sb = B32 + (size_t)(n0 + row) * KK + k0 + col;
        i32x4 av, bv;
#pragma unroll
        for (int t = 0; t < 4; ++t) {
          i32x4 ta = ((const i32x4*)sa)[t];
          i32x4 tb = ((const i32x4*)sb)[t];
          av[t] = pack4(ta[0], ta[1], ta[2], ta[3]);
          bv[t] = pack4(tb[0], tb[1], tb[2], tb[3]);
        }
        *(i32x4*)(&As[buf][p]) = av;
        *(i32x4*)(&Bs[buf][p]) = bv;
      }
    }
  };

  // Conflict-free swizzled reads: 32 lanes x 16B spread over all 32 banks
  // in 8 passes (the b128 wave64 minimum).
  auto compute = [&](int buf) {
#pragma unroll
    for (int ks = 0; ks < 4; ++ks) {
      i32x4 af[2], bf[2];
#pragma unroll
      for (int mi = 0; mi < 2; ++mi) {
        const int row = wr * 64 + mi * 32 + (lane & 31);
        int a = row * BK + ks * 32 + ((lane >> 5) << 4);
        a ^= (row & 7) << 4;
        af[mi] = *(const i32x4*)(&As[buf][a]);
      }
#pragma unroll
      for (int ni = 0; ni < 2; ++ni) {
        const int row = wc * 64 + ni * 32 + (lane & 31);
        int a = row * BK + ks * 32 + ((lane >> 5) << 4);
        a ^= (row & 7) << 4;
        bf[ni] = *(const i32x4*)(&Bs[buf][a]);
      }
#pragma unroll
      for (int mi = 0; mi < 2; ++mi)
#pragma unroll
        for (int ni = 0; ni < 2; ++ni)
          acc[mi][ni] = __builtin_amdgcn_mfma_i32_32x32x32_i8(
              af[mi], bf[ni], acc[mi][ni], 0, 0, 0);
    }
  };

  // T3 minimum-2-phase: stage k+1 before computing k; one barrier (which
  // drains vmcnt(0)+lgkmcnt(0)) per K-step. Next-buffer writes can only
  // land after the barrier that ended that buffer's reads.
  stage(0, 0);
  __syncthreads();
  for (int kt = 0; kt < NKT; ++kt) {
    if (kt + 1 < NKT) stage((kt + 1) & 1, kt + 1);
    compute(kt & 1);
    __syncthreads();
  }

  // Wave max of |acc| -> atomicMax
  int mx = 0;
#pragma unroll
  for (int mi = 0; mi < 2; ++mi)
#pragma unroll
    for (int ni = 0; ni < 2; ++ni)
#pragma unroll
      for (int rg = 0; rg < 16; ++rg) {
        int x = acc[mi][ni][rg];
        int a = x < 0 ? -x : x;
        mx = a > mx ? a : mx;
      }
#pragma unroll
  for (int off = 32; off >= 1; off >>= 1) {
    int o = __shfl_xor(mx, off);
    mx = o > mx ? o : mx;
  }
  if (lane == 0) atomicMax(maxslot, (unsigned)mx);

  // Store raw acc (C/D map: col=lane&31, row=(rg&3)+8*(rg>>2)+4*(lane>>5))
#pragma unroll
  for (int mi = 0; mi < 2; ++mi)
#pragma unroll
    for (int ni = 0; ni < 2; ++ni) {
      const int mbase = m0 + wr * 64 + mi * 32;
      const int ncol  = n0 + wc * 64 + ni * 32 + (lane & 31);
#pragma unroll
      for (int rg = 0; rg < 16; ++rg) {
        const int mrow = mbase + (rg & 3) + ((rg >> 2) << 3) + ((lane >> 5) << 2);
        out[(size_t)mrow * NN + ncol] = acc[mi][ni][rg];
      }
    }
}

// In-place requantize d_out[0..M*N) using max from maxslot. BW-bound.
__global__ __launch_bounds__(256)
void k_requant(int* __restrict__ out, const unsigned* __restrict__ maxslot) {
  const unsigned r = *maxslot;
  const int bits  = (r <= 1u) ? 0 : (32 - __clz((int)(r - 1u)));
  const int shift = bits - 7;  // BITWIDTH = 7
  const size_t n = (size_t)MM * NN;
  size_t i = ((size_t)blockIdx.x * blockDim.x + threadIdx.x) * 4;
  const size_t stride = (size_t)gridDim.x * blockDim.x * 4;
  if (shift > 0) {
    for (; i < n; i += stride) {
      i32x4 v = *(i32x4*)(out + i);
#pragma unroll
      for (int j = 0; j < 4; ++j) {
        const int x = v[j];
        int t = (x >> shift) + ((x >> (shift - 1)) & 1);
        v[j] = t > 127 ? 127 : (t < -127 ? -127 : t);
      }
      *(i32x4*)(out + i) = v;
    }
  } else {
    for (; i < n; i += stride) {
      i32x4 v = *(i32x4*)(out + i);
#pragma unroll
      for (int j = 0; j < 4; ++j) v[j] = (int)(int8_t)v[j];
      *(i32x4*)(out + i) = v;
    }
  }
}

__global__ void k_final(int* __restrict__ out, const int* __restrict__ exp_in,
                        const int* __restrict__ wexp) {
  if (threadIdx.x == 0) {
    const unsigned r = *(const unsigned*)(out + (size_t)MM * NN);
    const int bits  = (r <= 1u) ? 0 : (32 - __clz((int)(r - 1u)));
    const int shift = bits - 7;
    out[(size_t)MM * NN] = *exp_in + *wexp + (shift > 0 ? shift : 0);
  }
}

extern "C" void kernel_launch(void* const* d_in, const int* in_sizes, int n_in,
                              void* d_out, int out_size, void* d_ws, size_t ws_size,
                              hipStream_t stream) {
  const int* act    = (const int*)d_in[0];
  const int* wgt    = (const int*)d_in[1];
  const int* exp_in = (const int*)d_in[2];
  const int* wexp   = (const int*)d_in[3];
  int* out          = (int*)d_out;
  unsigned* maxslot = (unsigned*)(out + (size_t)MM * NN);  // spare exp slot

  const size_t need = (size_t)(MM + NN) * KK + 256;
  const int gemm_grid = (MM / BM) * (NN / BN);  // 2048 (multiple of 8)

  k_init<<<1, 64, 0, stream>>>(maxslot);

  if (ws_size >= need) {
    int8_t* a8 = (int8_t*)d_ws;
    int8_t* w8 = a8 + (size_t)MM * KK;
    k_pack<<<2048, 256, 0, stream>>>(act, a8, MM * KK);
    k_pack<<<256, 256, 0, stream>>>(wgt, w8, NN * KK);
    k_gemm<true><<<gemm_grid, 256, 0, stream>>>(a8, w8, out, maxslot);
  } else {
    k_gemm<false><<<gemm_grid, 256, 0, stream>>>(act, wgt, out, maxslot);
  }

  k_requant<<<4096, 256, 0, stream>>>(out, maxslot);
  k_final<<<1, 64, 0, stream>>>(out, exp_in, wexp);
}

// Round 3
// 170.108 us; speedup vs baseline: 1.3556x; 1.1679x over previous
//
#include <hip/hip_runtime.h>
#include <stdint.h>

// TiLinear: int8 GEMM [32768,1024] x [1024,1024]^T (int32 acc) -> global
// range-estimate -> round-shift requantize to int8 (stored as int32) + exp.
//
// Round 3: 256x256 GEMM tile, 8 waves (2M x 4N), BK=128B, dbuf 128KB LDS,
// 64 MFMA per wave per K-tile between barriers (4x round 2), front-loaded
// prefetch so the per-tile vmcnt(0) drain hits ~2300-cycle-old loads.

#define MM 32768
#define NN 1024
#define KK 1024
#define BM 256
#define BN 256
#define BK 128
#define NKT (KK / BK)  // 8

typedef __attribute__((ext_vector_type(4))) int i32x4;
typedef __attribute__((ext_vector_type(16))) int i32x16;

__device__ __forceinline__ int pack4(int a, int b, int c, int d) {
  return (int)((unsigned)(a & 0xff) | ((unsigned)(b & 0xff) << 8) |
               ((unsigned)(c & 0xff) << 16) | ((unsigned)(d & 0xff) << 24));
}

__global__ void k_init(unsigned* slot) {
  if (threadIdx.x == 0) *slot = 0u;
}

// Pack sign-extended-int8-in-int32 -> raw int8. n multiple of 16.
__global__ void k_pack(const int* __restrict__ src, int8_t* __restrict__ dst, int n) {
  long t = (long)blockIdx.x * blockDim.x + threadIdx.x;
  long stride = (long)gridDim.x * blockDim.x;
  for (long i = t * 16; i < (long)n; i += stride * 16) {
    const i32x4* s = (const i32x4*)(src + i);
    i32x4 a0 = s[0], a1 = s[1], a2 = s[2], a3 = s[3];
    i32x4 o;
    o[0] = pack4(a0[0], a0[1], a0[2], a0[3]);
    o[1] = pack4(a1[0], a1[1], a1[2], a1[3]);
    o[2] = pack4(a2[0], a2[1], a2[2], a2[3]);
    o[3] = pack4(a3[0], a3[1], a3[2], a3[3]);
    *(i32x4*)(dst + i) = o;
  }
}

// 256x256 tile, 8 waves (wm = w>>2 in {0,1}: 128 rows; wn = w&3: 64 cols).
// Per wave: acc[4][2] of 32x32 frags = 128 VGPRs.
// LDS: 2 x 32KB per matrix (dbuf), XOR-swizzled (byte ^= (row&7)<<4).
template <bool PACKED>
__global__ __launch_bounds__(512, 2)
void k_gemm(const void* __restrict__ Ap, const void* __restrict__ Bp,
            int* __restrict__ out, unsigned* __restrict__ maxslot) {
  __shared__ int8_t As[2][BM * BK];
  __shared__ int8_t Bs[2][BN * BK];

  const int tid  = threadIdx.x;
  const int lane = tid & 63;
  const int w    = tid >> 6;
  const int wm   = w >> 2;  // 0..1 -> 128-row half
  const int wn   = w & 3;   // 0..3 -> 64-col slice

  // XCD-bijective swizzle: 512 wgs, 8 XCDs, 64-wg contiguous chunks.
  // Chunk = 16 bm-panels x 4 bn => 4MB of A per XCD = its L2.
  const int orig = blockIdx.x;
  const int wgid = ((orig & 7) << 6) + (orig >> 3);
  const int bn = wgid & 3;
  const int bm = wgid >> 2;
  const int m0 = bm * BM;
  const int n0 = bn * BN;

  i32x16 acc[4][2];
#pragma unroll
  for (int i = 0; i < 4; ++i)
#pragma unroll
    for (int j = 0; j < 2; ++j) acc[i][j] = 0;

  // Stage K-tile kt into buffer buf: 64KB total, 8KB per wave
  // (4 x 1KB gload_lds for A, 4 for B). LDS dest is linear; the XOR
  // swizzle is carried by the per-lane SOURCE address (rule 21).
  auto stage = [&](int buf, int kt) {
    const int k0 = kt * BK;
#pragma unroll
    for (int q = 0; q < 4; ++q) {
      const int p   = (w * 4 + q) * 1024 + lane * 16;
      const int row = p >> 7;  // 128B per row
      const int col = (p & 127) ^ ((row & 7) << 4);
      if constexpr (PACKED) {
        const int8_t* A8 = (const int8_t*)Ap;
        const int8_t* B8 = (const int8_t*)Bp;
        __builtin_amdgcn_global_load_lds(
            (const __attribute__((address_space(1))) void*)(A8 + (size_t)(m0 + row) * KK + k0 + col),
            (__attribute__((address_space(3))) void*)(&As[buf][(w * 4 + q) * 1024]),
            16, 0, 0);
        __builtin_amdgcn_global_load_lds(
            (const __attribute__((address_space(1))) void*)(B8 + (size_t)(n0 + row) * KK + k0 + col),
            (__attribute__((address_space(3))) void*)(&Bs[buf][(w * 4 + q) * 1024]),
            16, 0, 0);
      } else {
        const int* A32 = (const int*)Ap;
        const int* B32 = (const int*)Bp;
        const int* sa = A32 + (size_t)(m0 + row) * KK + k0 + col;
        const int* sb = B32 + (size_t)(n0 + row) * KK + k0 + col;
        i32x4 av, bv;
#pragma unroll
        for (int t = 0; t < 4; ++t) {
          i32x4 ta = ((const i32x4*)sa)[t];
          i32x4 tb = ((const i32x4*)sb)[t];
          av[t] = pack4(ta[0], ta[1], ta[2], ta[3]);
          bv[t] = pack4(tb[0], tb[1], tb[2], tb[3]);
        }
        *(i32x4*)(&As[buf][p]) = av;
        *(i32x4*)(&Bs[buf][p]) = bv;
      }
    }
  };

  // 64 MFMA per wave per K-tile; 24 swizzled ds_read_b128.
  auto compute = [&](int buf) {
#pragma unroll
    for (int ks = 0; ks < 4; ++ks) {
      i32x4 af[4], bf[2];
#pragma unroll
      for (int ni = 0; ni < 2; ++ni) {
        const int row = wn * 64 + ni * 32 + (lane & 31);
        int a = row * BK + ks * 32 + ((lane >> 5) << 4);
        a ^= (row & 7) << 4;
        bf[ni] = *(const i32x4*)(&Bs[buf][a]);
      }
#pragma unroll
      for (int mi = 0; mi < 4; ++mi) {
        const int row = wm * 128 + mi * 32 + (lane & 31);
        int a = row * BK + ks * 32 + ((lane >> 5) << 4);
        a ^= (row & 7) << 4;
        af[mi] = *(const i32x4*)(&As[buf][a]);
      }
      __builtin_amdgcn_s_setprio(1);
#pragma unroll
      for (int mi = 0; mi < 4; ++mi)
#pragma unroll
        for (int ni = 0; ni < 2; ++ni)
          acc[mi][ni] = __builtin_amdgcn_mfma_i32_32x32x32_i8(
              af[mi], bf[ni], acc[mi][ni], 0, 0, 0);
      __builtin_amdgcn_s_setprio(0);
    }
  };

  stage(0, 0);
  __syncthreads();
  for (int kt = 0; kt < NKT; ++kt) {
    if (kt + 1 < NKT) stage((kt + 1) & 1, kt + 1);  // front-loaded prefetch
    compute(kt & 1);
    __syncthreads();  // drains vmcnt(0): prefetch is ~1 full tile old here
  }

  // Wave max of |acc| -> atomicMax
  int mx = 0;
#pragma unroll
  for (int mi = 0; mi < 4; ++mi)
#pragma unroll
    for (int ni = 0; ni < 2; ++ni)
#pragma unroll
      for (int rg = 0; rg < 16; ++rg) {
        int x = acc[mi][ni][rg];
        int a = x < 0 ? -x : x;
        mx = a > mx ? a : mx;
      }
#pragma unroll
  for (int off = 32; off >= 1; off >>= 1) {
    int o = __shfl_xor(mx, off);
    mx = o > mx ? o : mx;
  }
  if (lane == 0) atomicMax(maxslot, (unsigned)mx);

  // Store raw acc (C/D map: col=lane&31, row=(rg&3)+8*(rg>>2)+4*(lane>>5))
#pragma unroll
  for (int mi = 0; mi < 4; ++mi)
#pragma unroll
    for (int ni = 0; ni < 2; ++ni) {
      const int mbase = m0 + wm * 128 + mi * 32;
      const int ncol  = n0 + wn * 64 + ni * 32 + (lane & 31);
#pragma unroll
      for (int rg = 0; rg < 16; ++rg) {
        const int mrow = mbase + (rg & 3) + ((rg >> 2) << 3) + ((lane >> 5) << 2);
        out[(size_t)mrow * NN + ncol] = acc[mi][ni][rg];
      }
    }
}

// In-place requantize d_out[0..M*N) using max from maxslot. BW-bound.
__global__ __launch_bounds__(256)
void k_requant(int* __restrict__ out, const unsigned* __restrict__ maxslot) {
  const unsigned r = *maxslot;
  const int bits  = (r <= 1u) ? 0 : (32 - __clz((int)(r - 1u)));
  const int shift = bits - 7;  // BITWIDTH = 7
  const size_t n = (size_t)MM * NN;
  size_t i = ((size_t)blockIdx.x * blockDim.x + threadIdx.x) * 4;
  const size_t stride = (size_t)gridDim.x * blockDim.x * 4;
  if (shift > 0) {
    for (; i < n; i += stride) {
      i32x4 v = *(i32x4*)(out + i);
#pragma unroll
      for (int j = 0; j < 4; ++j) {
        const int x = v[j];
        int t = (x >> shift) + ((x >> (shift - 1)) & 1);
        v[j] = t > 127 ? 127 : (t < -127 ? -127 : t);
      }
      *(i32x4*)(out + i) = v;
    }
  } else {
    for (; i < n; i += stride) {
      i32x4 v = *(i32x4*)(out + i);
#pragma unroll
      for (int j = 0; j < 4; ++j) v[j] = (int)(int8_t)v[j];
      *(i32x4*)(out + i) = v;
    }
  }
}

__global__ void k_final(int* __restrict__ out, const int* __restrict__ exp_in,
                        const int* __restrict__ wexp) {
  if (threadIdx.x == 0) {
    const unsigned r = *(const unsigned*)(out + (size_t)MM * NN);
    const int bits  = (r <= 1u) ? 0 : (32 - __clz((int)(r - 1u)));
    const int shift = bits - 7;
    out[(size_t)MM * NN] = *exp_in + *wexp + (shift > 0 ? shift : 0);
  }
}

extern "C" void kernel_launch(void* const* d_in, const int* in_sizes, int n_in,
                              void* d_out, int out_size, void* d_ws, size_t ws_size,
                              hipStream_t stream) {
  const int* act    = (const int*)d_in[0];
  const int* wgt    = (const int*)d_in[1];
  const int* exp_in = (const int*)d_in[2];
  const int* wexp   = (const int*)d_in[3];
  int* out          = (int*)d_out;
  unsigned* maxslot = (unsigned*)(out + (size_t)MM * NN);  // spare exp slot

  const size_t need = (size_t)(MM + NN) * KK + 256;
  const int gemm_grid = (MM / BM) * (NN / BN);  // 512 (multiple of 8)

  k_init<<<1, 64, 0, stream>>>(maxslot);

  if (ws_size >= need) {
    int8_t* a8 = (int8_t*)d_ws;
    int8_t* w8 = a8 + (size_t)MM * KK;
    k_pack<<<2048, 256, 0, stream>>>(act, a8, MM * KK);
    k_pack<<<256, 256, 0, stream>>>(wgt, w8, NN * KK);
    k_gemm<true><<<gemm_grid, 512, 0, stream>>>(a8, w8, out, maxslot);
  } else {
    k_gemm<false><<<gemm_grid, 512, 0, stream>>>(act, wgt, out, maxslot);
  }

  k_requant<<<4096, 256, 0, stream>>>(out, maxslot);
  k_final<<<1, 64, 0, stream>>>(out, exp_in, wexp);
}